// Round 1
// baseline (581.594 us; speedup 1.0000x reference)
//
#include <hip/hip_runtime.h>

typedef unsigned short u16;
typedef unsigned int   u32;
typedef __bf16  bf16x8 __attribute__((ext_vector_type(8)));
typedef float   f32x4  __attribute__((ext_vector_type(4)));

static __device__ __forceinline__ float b2f(u16 v) {
    return __builtin_bit_cast(float, (u32)(((u32)v) << 16));
}
static __device__ __forceinline__ u16 f2b(float f) {  // RNE f32->bf16
    u32 u = __builtin_bit_cast(u32, f);
    return (u16)((u + 0x7FFFu + ((u >> 16) & 1u)) >> 16);
}

// ---------------------------------------------------------------------------
// LayerNorm: rows 0..4095 = x, 4096..8191 = context. 1024 f32 per row.
// ---------------------------------------------------------------------------
__global__ __launch_bounds__(256)
void ln_kernel(const float* __restrict__ x, const float* __restrict__ ctx,
               const float* __restrict__ gamma, const float* __restrict__ cgamma,
               u16* __restrict__ xn, u16* __restrict__ ctxn)
{
    const int row = blockIdx.x;
    const int tid = threadIdx.x;
    const float* src; const float* g; u16* dst;
    if (row < 4096) { src = x   + (long)row * 1024;          g = gamma;  dst = xn   + (long)row * 1024; }
    else            { src = ctx + (long)(row - 4096) * 1024; g = cgamma; dst = ctxn + (long)(row - 4096) * 1024; }
    float4 v = ((const float4*)src)[tid];
    float s = v.x + v.y + v.z + v.w;
    float q = v.x*v.x + v.y*v.y + v.z*v.z + v.w*v.w;
#pragma unroll
    for (int off = 32; off; off >>= 1) { s += __shfl_xor(s, off); q += __shfl_xor(q, off); }
    __shared__ float r1[4], r2[4];
    if ((tid & 63) == 0) { r1[tid >> 6] = s; r2[tid >> 6] = q; }
    __syncthreads();
    s = r1[0] + r1[1] + r1[2] + r1[3];
    q = r2[0] + r2[1] + r2[2] + r2[3];
    float mu   = s * (1.0f / 1024.0f);
    float var  = q * (1.0f / 1024.0f) - mu * mu;
    float rstd = rsqrtf(var + 1e-5f);
    float4 gv = ((const float4*)g)[tid];
    ushort4 o;
    o.x = f2b((v.x - mu) * rstd * gv.x);
    o.y = f2b((v.y - mu) * rstd * gv.y);
    o.z = f2b((v.z - mu) * rstd * gv.z);
    o.w = f2b((v.w - mu) * rstd * gv.w);
    ((ushort4*)dst)[tid] = o;
}

// ---------------------------------------------------------------------------
// Weight convert: W f32 [K][N] row-major -> Wt bf16 [N][K] row-major, *scale
// grid (N/32, K/32), 256 threads, LDS 32x33 transpose tile.
// ---------------------------------------------------------------------------
__global__ __launch_bounds__(256)
void wconv(const float* __restrict__ W, u16* __restrict__ Wt, int N, int K, float scale)
{
    __shared__ float tile[32][33];
    const int tid = threadIdx.x;
    const int n0 = blockIdx.x * 32;
    const int k0 = blockIdx.y * 32;
    const int r  = tid >> 3;
    const int c4 = (tid & 7) * 4;
    float4 v = *(const float4*)&W[(long)(k0 + r) * N + n0 + c4];
    tile[r][c4 + 0] = v.x; tile[r][c4 + 1] = v.y; tile[r][c4 + 2] = v.z; tile[r][c4 + 3] = v.w;
    __syncthreads();
    ushort4 o;
    o.x = f2b(tile[c4 + 0][r] * scale);
    o.y = f2b(tile[c4 + 1][r] * scale);
    o.z = f2b(tile[c4 + 2][r] * scale);
    o.w = f2b(tile[c4 + 3][r] * scale);
    *(ushort4*)&Wt[(long)(n0 + r) * K + k0 + c4] = o;
}

// ---------------------------------------------------------------------------
// V transpose (padded): kv [2][2048][128] (v = cols 64..127) -> vT [2][128][2048]
// rows 64..127 of vT zero-filled (pads AV GEMM N to 128).
// ---------------------------------------------------------------------------
__global__ __launch_bounds__(256)
void vtrans(const u16* __restrict__ kv, u16* __restrict__ vT)
{
    const int j = blockIdx.x * 256 + threadIdx.x;
    const int d = blockIdx.y;
    const int b = blockIdx.z;
    u16 val = 0;
    if (d < 64) val = kv[(long)b * 2048 * 128 + (long)j * 128 + 64 + d];
    vT[(long)b * 128 * 2048 + (long)d * 2048 + j] = val;
}

// ---------------------------------------------------------------------------
// GEMM: C[M][N] = A[M][K](bf16,row-major,lda) @ Bt[N][K](bf16,row-major,ldb)^T
// 128x128 tile, BK=32, 256 thr (4 waves, 2x2), per-wave 64x64 = 4x4 frags of
// 16x16x32 MFMA. global_load_lds(16B) staging, double-buffered LDS, XOR
// chunk swizzle (chunk ^= (row>>1)&3) -> 2-way max bank aliasing (free).
// z-batched via element offsets aH/bH/cH. EPI: 0 bf16-store, 1 f32-store,
// 2 f32-accumulate.
// ---------------------------------------------------------------------------
#define BM 128
#define BN 128
#define BK 32

template<int EPI>
__global__ __launch_bounds__(256, 2)
void gemm_bt(const u16* __restrict__ A, const u16* __restrict__ Bt,
             void* __restrict__ Cv,
             int K, int lda, int ldb, int ldc,
             long aH, long bH, long cH)
{
    __shared__ __align__(16) u16 sm[2][2][BM * BK];
    const int tid  = threadIdx.x;
    const int wave = tid >> 6;
    const int lane = tid & 63;
    const int tn = blockIdx.x * BN;
    const int tm = blockIdx.y * BM;
    const int z  = blockIdx.z;
    A  += (long)z * aH;
    Bt += (long)z * bH;

    // staging geometry: slot s = i*256 + tid; phys row = s>>2, phys chunk = s&3;
    // source (logical) chunk = physChunk ^ ((row>>1)&3)
    const int arow0 = (tid >> 2);
    const int arow1 = 64 + (tid >> 2);
    const int acs0  = (tid & 3) ^ ((arow0 >> 1) & 3);
    const int acs1  = (tid & 3) ^ ((arow1 >> 1) & 3);
    const int nt = K / BK;

#define STAGE(buf, k0)                                                                              \
    do {                                                                                            \
        __builtin_amdgcn_global_load_lds(                                                           \
            (const __attribute__((address_space(1))) void*)(A + (long)(tm + arow0) * lda + (k0) + acs0 * 8),   \
            (__attribute__((address_space(3))) void*)(&sm[buf][0][(wave * 64) * 8]), 16, 0, 0);     \
        __builtin_amdgcn_global_load_lds(                                                           \
            (const __attribute__((address_space(1))) void*)(A + (long)(tm + arow1) * lda + (k0) + acs1 * 8),   \
            (__attribute__((address_space(3))) void*)(&sm[buf][0][(256 + wave * 64) * 8]), 16, 0, 0); \
        __builtin_amdgcn_global_load_lds(                                                           \
            (const __attribute__((address_space(1))) void*)(Bt + (long)(tn + arow0) * ldb + (k0) + acs0 * 8),  \
            (__attribute__((address_space(3))) void*)(&sm[buf][1][(wave * 64) * 8]), 16, 0, 0);     \
        __builtin_amdgcn_global_load_lds(                                                           \
            (const __attribute__((address_space(1))) void*)(Bt + (long)(tn + arow1) * ldb + (k0) + acs1 * 8),  \
            (__attribute__((address_space(3))) void*)(&sm[buf][1][(256 + wave * 64) * 8]), 16, 0, 0); \
    } while (0)

    STAGE(0, 0);

    f32x4 acc[4][4] = {};
    const int wr   = (wave >> 1) * 64;
    const int wc   = (wave & 1) * 64;
    const int frow = lane & 15;
    const int fk   = lane >> 4;

    for (int t = 0; t < nt; ++t) {
        __syncthreads();               // drains vmcnt -> buf[cur] staged; all waves done reading buf[cur^1]
        if (t + 1 < nt) STAGE((t + 1) & 1, (t + 1) * BK);
        const int cur = t & 1;
        bf16x8 af[4], bf[4];
#pragma unroll
        for (int m = 0; m < 4; ++m) {
            int row = wr + m * 16 + frow;
            af[m] = *(const bf16x8*)&sm[cur][0][row * BK + ((fk ^ ((row >> 1) & 3)) * 8)];
        }
#pragma unroll
        for (int n = 0; n < 4; ++n) {
            int row = wc + n * 16 + frow;
            bf[n] = *(const bf16x8*)&sm[cur][1][row * BK + ((fk ^ ((row >> 1) & 3)) * 8)];
        }
#pragma unroll
        for (int m = 0; m < 4; ++m)
#pragma unroll
            for (int n = 0; n < 4; ++n)
                acc[m][n] = __builtin_amdgcn_mfma_f32_16x16x32_bf16(af[m], bf[n], acc[m][n], 0, 0, 0);
    }
#undef STAGE

    const long coff = (long)z * cH;
#pragma unroll
    for (int m = 0; m < 4; ++m) {
        const int row0 = tm + wr + m * 16 + fk * 4;
#pragma unroll
        for (int n = 0; n < 4; ++n) {
            const int col = tn + wc + n * 16 + frow;
#pragma unroll
            for (int r = 0; r < 4; ++r) {
                const long off = coff + (long)(row0 + r) * ldc + col;
                const float v = acc[m][n][r];
                if constexpr (EPI == 0)      ((u16*)Cv)[off] = f2b(v);
                else if constexpr (EPI == 1) ((float*)Cv)[off] = v;
                else                         ((float*)Cv)[off] += v;
            }
        }
    }
}

// ---------------------------------------------------------------------------
// Masked softmax over rows of sim [16][2048][2048] bf16 (one batch), in-place.
// grid (2048 rows, 16 heads), 256 thr, 8 cols/thread.
// ---------------------------------------------------------------------------
__global__ __launch_bounds__(256)
void softmax_rows(u16* __restrict__ sim, const int* __restrict__ mask)
{
    const int tid = threadIdx.x;
    u16* row = sim + ((long)blockIdx.y * 2048 + blockIdx.x) * 2048;
    const int j0 = tid * 8;
    ushort4 a  = *(const ushort4*)&row[j0];
    ushort4 b  = *(const ushort4*)&row[j0 + 4];
    int4 m1 = *(const int4*)&mask[j0];
    int4 m2 = *(const int4*)&mask[j0 + 4];
    float s[8];
    s[0] = m1.x ? b2f(a.x) : -1e30f;
    s[1] = m1.y ? b2f(a.y) : -1e30f;
    s[2] = m1.z ? b2f(a.z) : -1e30f;
    s[3] = m1.w ? b2f(a.w) : -1e30f;
    s[4] = m2.x ? b2f(b.x) : -1e30f;
    s[5] = m2.y ? b2f(b.y) : -1e30f;
    s[6] = m2.z ? b2f(b.z) : -1e30f;
    s[7] = m2.w ? b2f(b.w) : -1e30f;
    float mx = s[0];
#pragma unroll
    for (int e = 1; e < 8; ++e) mx = fmaxf(mx, s[e]);
#pragma unroll
    for (int off = 32; off; off >>= 1) mx = fmaxf(mx, __shfl_xor(mx, off));
    __shared__ float red[8];
    if ((tid & 63) == 0) red[tid >> 6] = mx;
    __syncthreads();
    mx = fmaxf(fmaxf(red[0], red[1]), fmaxf(red[2], red[3]));
    float p[8], sum = 0.f;
#pragma unroll
    for (int e = 0; e < 8; ++e) { p[e] = __expf(s[e] - mx); sum += p[e]; }
#pragma unroll
    for (int off = 32; off; off >>= 1) sum += __shfl_xor(sum, off);
    if ((tid & 63) == 0) red[4 + (tid >> 6)] = sum;
    __syncthreads();
    sum = red[4] + red[5] + red[6] + red[7];
    const float inv = 1.0f / sum;
    ushort4 o1, o2;
    o1.x = f2b(p[0] * inv); o1.y = f2b(p[1] * inv); o1.z = f2b(p[2] * inv); o1.w = f2b(p[3] * inv);
    o2.x = f2b(p[4] * inv); o2.y = f2b(p[5] * inv); o2.z = f2b(p[6] * inv); o2.w = f2b(p[7] * inv);
    *(ushort4*)&row[j0]     = o1;
    *(ushort4*)&row[j0 + 4] = o2;
}

// ---------------------------------------------------------------------------
// av [2][16][2048][128] -> aperm [2][2048][16*64] (heads interleaved per row)
// ---------------------------------------------------------------------------
__global__ __launch_bounds__(256)
void avperm(const u16* __restrict__ av, u16* __restrict__ outp)
{
    const int bn = blockIdx.x;             // b*2048 + n
    const int b = bn >> 11, n = bn & 2047;
    const int idx = threadIdx.x * 4;       // 0..1023
    const int h = idx >> 6, d = idx & 63;
    ushort4 v = *(const ushort4*)&av[(((long)(b * 16 + h) * 2048 + n) << 7) + d];
    *(ushort4*)&outp[(long)bn * 1024 + idx] = v;
}

// ---------------------------------------------------------------------------
// SwiGLU: h [4096][8192] bf16; a = h[:, :4096], gate = h[:, 4096:];
// g[r][c] = silu(gate)*a. 8 elems/thread.
// ---------------------------------------------------------------------------
__global__ __launch_bounds__(256)
void swiglu(const u16* __restrict__ hbuf, u16* __restrict__ gbuf)
{
    const long t = (long)blockIdx.x * 256 + threadIdx.x;
    const int r = (int)(t >> 9);
    const int c = ((int)t & 511) * 8;
    const u16* hrow = hbuf + (long)r * 8192;
    ushort4 a1 = *(const ushort4*)&hrow[c];
    ushort4 a2 = *(const ushort4*)&hrow[c + 4];
    ushort4 g1 = *(const ushort4*)&hrow[4096 + c];
    ushort4 g2 = *(const ushort4*)&hrow[4096 + c + 4];
    float av[8] = {b2f(a1.x), b2f(a1.y), b2f(a1.z), b2f(a1.w),
                   b2f(a2.x), b2f(a2.y), b2f(a2.z), b2f(a2.w)};
    float gv[8] = {b2f(g1.x), b2f(g1.y), b2f(g1.z), b2f(g1.w),
                   b2f(g2.x), b2f(g2.y), b2f(g2.z), b2f(g2.w)};
    float o[8];
#pragma unroll
    for (int e = 0; e < 8; ++e) o[e] = av[e] * gv[e] / (1.0f + __expf(-gv[e]));
    ushort4 o1, o2;
    o1.x = f2b(o[0]); o1.y = f2b(o[1]); o1.z = f2b(o[2]); o1.w = f2b(o[3]);
    o2.x = f2b(o[4]); o2.y = f2b(o[5]); o2.z = f2b(o[6]); o2.w = f2b(o[7]);
    *(ushort4*)&gbuf[(long)r * 4096 + c]     = o1;
    *(ushort4*)&gbuf[(long)r * 4096 + c + 4] = o2;
}

// ---------------------------------------------------------------------------
extern "C" void kernel_launch(void* const* d_in, const int* in_sizes, int n_in,
                              void* d_out, int out_size, void* d_ws, size_t ws_size,
                              hipStream_t stream)
{
    const float* x      = (const float*)d_in[0];
    const float* ctx    = (const float*)d_in[1];
    const int*   mask   = (const int*)d_in[2];
    const float* gamma  = (const float*)d_in[3];
    const float* cgamma = (const float*)d_in[4];
    const float* Wq     = (const float*)d_in[5];
    const float* Wkv    = (const float*)d_in[6];
    const float* Wout   = (const float*)d_in[7];
    const float* Wff1   = (const float*)d_in[8];
    const float* Wff2   = (const float*)d_in[9];
    float* out = (float*)d_out;

    char* w = (char*)d_ws;
    auto carve = [&](long elems) { u16* p = (u16*)w; w += ((elems * 2 + 255) / 256) * 256; return p; };
    u16* xn    = carve(4096L * 1024);
    u16* ctxn  = carve(4096L * 1024);
    u16* WqT   = carve(1024L * 1024);
    u16* WkvT  = carve(128L * 1024);
    u16* WoutT = carve(1024L * 1024);
    u16* Wff1T = carve(8192L * 1024);
    u16* Wff2T = carve(1024L * 4096);
    u16* q     = carve(4096L * 1024);
    u16* kv    = carve(4096L * 128);
    u16* vT    = carve(2L * 128 * 2048);
    u16* av    = carve(2L * 16 * 2048 * 128);
    u16* aperm = carve(4096L * 1024);
    u16* sim   = carve(16L * 2048 * 2048);   // per-batch reuse; h/g alias after attention
    u16* hbuf  = sim;                         // 4096*8192 = 64MB  (sim region is 128MB)
    u16* gbuf  = sim + 33554432L;             // 4096*4096 = 32MB

    dim3 B(256);

    ln_kernel<<<dim3(8192), B, 0, stream>>>(x, ctx, gamma, cgamma, xn, ctxn);
    wconv<<<dim3(32, 32),  B, 0, stream>>>(Wq,   WqT,   1024, 1024, 0.125f);  // scale folded
    wconv<<<dim3(4, 32),   B, 0, stream>>>(Wkv,  WkvT,  128,  1024, 1.0f);
    wconv<<<dim3(32, 32),  B, 0, stream>>>(Wout, WoutT, 1024, 1024, 1.0f);
    wconv<<<dim3(256, 32), B, 0, stream>>>(Wff1, Wff1T, 8192, 1024, 1.0f);
    wconv<<<dim3(32, 128), B, 0, stream>>>(Wff2, Wff2T, 1024, 4096, 1.0f);

    // q = xn @ WqT^T : M=4096 N=1024 K=1024
    gemm_bt<0><<<dim3(8, 32, 1), B, 0, stream>>>(xn, WqT, q, 1024, 1024, 1024, 1024, 0, 0, 0);
    // kv = ctxn @ WkvT^T : M=4096 N=128 K=1024
    gemm_bt<0><<<dim3(1, 32, 1), B, 0, stream>>>(ctxn, WkvT, kv, 1024, 1024, 1024, 128, 0, 0, 0);
    vtrans<<<dim3(8, 128, 2), B, 0, stream>>>(kv, vT);

    for (int b = 0; b < 2; ++b) {
        // sim[h] = Q_bh (2048x64, lda=1024, head offset 64) @ K_b^T : N=2048 K=64
        gemm_bt<0><<<dim3(16, 16, 16), B, 0, stream>>>(
            q + (long)b * 2048 * 1024, kv + (long)b * 2048 * 128, sim,
            64, 1024, 128, 2048, 64, 0, (long)2048 * 2048);
        softmax_rows<<<dim3(2048, 16), B, 0, stream>>>(sim, mask + b * 2048);
        // av[h] = attn (2048x2048) @ vT^T : N=128(pad) K=2048
        gemm_bt<0><<<dim3(1, 16, 16), B, 0, stream>>>(
            sim, vT + (long)b * 128 * 2048, av + (long)b * 16 * 2048 * 128,
            2048, 2048, 2048, 128, (long)2048 * 2048, 0, (long)2048 * 128);
    }
    avperm<<<dim3(4096), B, 0, stream>>>(av, aperm);
    // out = aperm @ WoutT^T (f32 write)
    gemm_bt<1><<<dim3(8, 32, 1), B, 0, stream>>>(aperm, WoutT, out, 1024, 1024, 1024, 1024, 0, 0, 0);
    // h = xn @ Wff1T^T : N=8192
    gemm_bt<0><<<dim3(64, 32, 1), B, 0, stream>>>(xn, Wff1T, hbuf, 1024, 1024, 1024, 8192, 0, 0, 0);
    swiglu<<<dim3(8192), B, 0, stream>>>(hbuf, gbuf);
    // out += g @ Wff2T^T : K=4096 (f32 accumulate)
    gemm_bt<2><<<dim3(8, 32, 1), B, 0, stream>>>(gbuf, Wff2T, out, 4096, 4096, 4096, 1024, 0, 0, 0);
}

// Round 2
// 495.522 us; speedup vs baseline: 1.1737x; 1.1737x over previous
//
#include <hip/hip_runtime.h>

typedef unsigned short u16;
typedef unsigned int   u32;
typedef __bf16  bf16x8 __attribute__((ext_vector_type(8)));
typedef __bf16  bf16x2 __attribute__((ext_vector_type(2)));
typedef u16     u16x8  __attribute__((ext_vector_type(8)));
typedef float   f32x4  __attribute__((ext_vector_type(4)));

static __device__ __forceinline__ float b2f(u16 v) {
    return __builtin_bit_cast(float, (u32)(((u32)v) << 16));
}
static __device__ __forceinline__ u16 f2b(float f) {  // RNE f32->bf16
    u32 u = __builtin_bit_cast(u32, f);
    return (u16)((u + 0x7FFFu + ((u >> 16) & 1u)) >> 16);
}
static __device__ __forceinline__ u32 pack2(float a, float b) {
    bf16x2 t; t[0] = (__bf16)a; t[1] = (__bf16)b;
    return __builtin_bit_cast(u32, t);
}

// ---------------------------------------------------------------------------
// LayerNorm: rows 0..4095 = x, 4096..8191 = context. 1024 f32 per row.
// ---------------------------------------------------------------------------
__global__ __launch_bounds__(256)
void ln_kernel(const float* __restrict__ x, const float* __restrict__ ctx,
               const float* __restrict__ gamma, const float* __restrict__ cgamma,
               u16* __restrict__ xn, u16* __restrict__ ctxn)
{
    const int row = blockIdx.x;
    const int tid = threadIdx.x;
    const float* src; const float* g; u16* dst;
    if (row < 4096) { src = x   + (long)row * 1024;          g = gamma;  dst = xn   + (long)row * 1024; }
    else            { src = ctx + (long)(row - 4096) * 1024; g = cgamma; dst = ctxn + (long)(row - 4096) * 1024; }
    float4 v = ((const float4*)src)[tid];
    float s = v.x + v.y + v.z + v.w;
    float q = v.x*v.x + v.y*v.y + v.z*v.z + v.w*v.w;
#pragma unroll
    for (int off = 32; off; off >>= 1) { s += __shfl_xor(s, off); q += __shfl_xor(q, off); }
    __shared__ float r1[4], r2[4];
    if ((tid & 63) == 0) { r1[tid >> 6] = s; r2[tid >> 6] = q; }
    __syncthreads();
    s = r1[0] + r1[1] + r1[2] + r1[3];
    q = r2[0] + r2[1] + r2[2] + r2[3];
    float mu   = s * (1.0f / 1024.0f);
    float var  = q * (1.0f / 1024.0f) - mu * mu;
    float rstd = rsqrtf(var + 1e-5f);
    float4 gv = ((const float4*)g)[tid];
    ushort4 o;
    o.x = f2b((v.x - mu) * rstd * gv.x);
    o.y = f2b((v.y - mu) * rstd * gv.y);
    o.z = f2b((v.z - mu) * rstd * gv.z);
    o.w = f2b((v.w - mu) * rstd * gv.w);
    ((ushort4*)dst)[tid] = o;
}

// ---------------------------------------------------------------------------
// Weight convert: W f32 [K][N] row-major -> Wt bf16 [N][K] row-major, *scale
// ---------------------------------------------------------------------------
__global__ __launch_bounds__(256)
void wconv(const float* __restrict__ W, u16* __restrict__ Wt, int N, int K, float scale)
{
    __shared__ float tile[32][33];
    const int tid = threadIdx.x;
    const int n0 = blockIdx.x * 32;
    const int k0 = blockIdx.y * 32;
    const int r  = tid >> 3;
    const int c4 = (tid & 7) * 4;
    float4 v = *(const float4*)&W[(long)(k0 + r) * N + n0 + c4];
    tile[r][c4 + 0] = v.x; tile[r][c4 + 1] = v.y; tile[r][c4 + 2] = v.z; tile[r][c4 + 3] = v.w;
    __syncthreads();
    ushort4 o;
    o.x = f2b(tile[c4 + 0][r] * scale);
    o.y = f2b(tile[c4 + 1][r] * scale);
    o.z = f2b(tile[c4 + 2][r] * scale);
    o.w = f2b(tile[c4 + 3][r] * scale);
    *(ushort4*)&Wt[(long)(n0 + r) * K + k0 + c4] = o;
}

// ---------------------------------------------------------------------------
// Wff1 convert with a/gate interleave: phys row p (0..8191) <- logical col
// L(p) = (p&16 ? 4096:0) + (p>>5)*16 + (p&15). So FF1 output tile pairs
// (n even = a, n odd = gate) share the same silu output column.
// ---------------------------------------------------------------------------
__global__ __launch_bounds__(256)
void wconv_ff1(const float* __restrict__ W, u16* __restrict__ Wt)
{
    __shared__ float tile[32][33];
    const int tid = threadIdx.x;
    const int a  = blockIdx.x;            // 0..255
    const int k0 = blockIdx.y * 32;
    const int r  = tid >> 3;
    const int c4 = (tid & 7) * 4;
    const int srccol = (c4 < 16) ? (a * 16 + c4) : (4096 + a * 16 + (c4 - 16));
    float4 v = *(const float4*)&W[(long)(k0 + r) * 8192 + srccol];
    tile[r][c4 + 0] = v.x; tile[r][c4 + 1] = v.y; tile[r][c4 + 2] = v.z; tile[r][c4 + 3] = v.w;
    __syncthreads();
    ushort4 o;
    o.x = f2b(tile[c4 + 0][r]);
    o.y = f2b(tile[c4 + 1][r]);
    o.z = f2b(tile[c4 + 2][r]);
    o.w = f2b(tile[c4 + 3][r]);
    *(ushort4*)&Wt[(long)(a * 32 + r) * 1024 + k0 + c4] = o;
}

// ---------------------------------------------------------------------------
// kext: [2][2048][96] bf16: cols 0..63 = K (from kvf f32), col 64 = mask bias
// (0 if kept, -1e30 if masked), cols 65..95 = 0.
// ---------------------------------------------------------------------------
__global__ __launch_bounds__(256)
void kext_build(const float* __restrict__ kvf, const int* __restrict__ mask,
                u16* __restrict__ kext)
{
    const int gid = blockIdx.x * 256 + threadIdx.x;   // 2*2048*12 = 49152
    if (gid >= 49152) return;
    const int b = gid / (2048 * 12);
    const int rem = gid - b * (2048 * 12);
    const int j = rem / 12;
    const int c = rem - j * 12;
    u16 ov[8];
    if (c < 8) {
        const float* src = &kvf[((long)b * 2048 + j) * 128 + c * 8];
#pragma unroll
        for (int e = 0; e < 8; ++e) ov[e] = f2b(src[e]);
    } else {
#pragma unroll
        for (int e = 0; e < 8; ++e) ov[e] = 0;
        if (c == 8) ov[0] = mask[b * 2048 + j] ? (u16)0 : f2b(-1e30f);
    }
    uint4 w;
    w.x = (u32)ov[0] | ((u32)ov[1] << 16);
    w.y = (u32)ov[2] | ((u32)ov[3] << 16);
    w.z = (u32)ov[4] | ((u32)ov[5] << 16);
    w.w = (u32)ov[6] | ((u32)ov[7] << 16);
    *(uint4*)&kext[((long)b * 2048 + j) * 96 + c * 8] = w;
}

// ---------------------------------------------------------------------------
// vT [2][64][2048] bf16 <- V columns of kvf f32 [2][2048][128]
// ---------------------------------------------------------------------------
__global__ __launch_bounds__(256)
void vtrans(const float* __restrict__ kvf, u16* __restrict__ vT)
{
    const int j = blockIdx.x * 256 + threadIdx.x;
    const int d = blockIdx.y;
    const int b = blockIdx.z;
    vT[(long)b * 64 * 2048 + (long)d * 2048 + j] =
        f2b(kvf[((long)b * 2048 + j) * 128 + 64 + d]);
}

// ---------------------------------------------------------------------------
// GEMM: C[M][N] = A[M][K](bf16) @ Bt[N][K](bf16)^T.  128x128 tile, BK=32.
// EPI: 0 bf16-store, 1 f32-store, 2 f32-accumulate, 3 swiglu(bf16, paired
// cols), 4 f32 atomic-accumulate (split-K).
// ---------------------------------------------------------------------------
#define BM 128
#define BN 128
#define BK 32

template<int EPI>
__global__ __launch_bounds__(256, 2)
void gemm_bt(const u16* __restrict__ A, const u16* __restrict__ Bt,
             void* __restrict__ Cv,
             int K, int lda, int ldb, int ldc,
             long aH, long bH, long cH)
{
    __shared__ __align__(16) u16 sm[2][2][BM * BK];
    const int tid  = threadIdx.x;
    const int wave = tid >> 6;
    const int lane = tid & 63;
    const int tn = blockIdx.x * BN;
    const int tm = blockIdx.y * BM;
    const int z  = blockIdx.z;
    A  += (long)z * aH;
    Bt += (long)z * bH;

    const int arow0 = (tid >> 2);
    const int arow1 = 64 + (tid >> 2);
    const int acs0  = (tid & 3) ^ ((arow0 >> 1) & 3);
    const int acs1  = (tid & 3) ^ ((arow1 >> 1) & 3);
    const int nt = K / BK;

#define STAGE(buf, k0)                                                                              \
    do {                                                                                            \
        __builtin_amdgcn_global_load_lds(                                                           \
            (const __attribute__((address_space(1))) void*)(A + (long)(tm + arow0) * lda + (k0) + acs0 * 8),   \
            (__attribute__((address_space(3))) void*)(&sm[buf][0][(wave * 64) * 8]), 16, 0, 0);     \
        __builtin_amdgcn_global_load_lds(                                                           \
            (const __attribute__((address_space(1))) void*)(A + (long)(tm + arow1) * lda + (k0) + acs1 * 8),   \
            (__attribute__((address_space(3))) void*)(&sm[buf][0][(256 + wave * 64) * 8]), 16, 0, 0); \
        __builtin_amdgcn_global_load_lds(                                                           \
            (const __attribute__((address_space(1))) void*)(Bt + (long)(tn + arow0) * ldb + (k0) + acs0 * 8),  \
            (__attribute__((address_space(3))) void*)(&sm[buf][1][(wave * 64) * 8]), 16, 0, 0);     \
        __builtin_amdgcn_global_load_lds(                                                           \
            (const __attribute__((address_space(1))) void*)(Bt + (long)(tn + arow1) * ldb + (k0) + acs1 * 8),  \
            (__attribute__((address_space(3))) void*)(&sm[buf][1][(256 + wave * 64) * 8]), 16, 0, 0); \
    } while (0)

    STAGE(0, 0);

    f32x4 acc[4][4] = {};
    const int wr   = (wave >> 1) * 64;
    const int wc   = (wave & 1) * 64;
    const int frow = lane & 15;
    const int fk   = lane >> 4;

    for (int t = 0; t < nt; ++t) {
        __syncthreads();
        if (t + 1 < nt) STAGE((t + 1) & 1, (t + 1) * BK);
        const int cur = t & 1;
        bf16x8 af[4], bf[4];
#pragma unroll
        for (int m = 0; m < 4; ++m) {
            int row = wr + m * 16 + frow;
            af[m] = *(const bf16x8*)&sm[cur][0][row * BK + ((fk ^ ((row >> 1) & 3)) * 8)];
        }
#pragma unroll
        for (int n = 0; n < 4; ++n) {
            int row = wc + n * 16 + frow;
            bf[n] = *(const bf16x8*)&sm[cur][1][row * BK + ((fk ^ ((row >> 1) & 3)) * 8)];
        }
#pragma unroll
        for (int m = 0; m < 4; ++m)
#pragma unroll
            for (int n = 0; n < 4; ++n)
                acc[m][n] = __builtin_amdgcn_mfma_f32_16x16x32_bf16(af[m], bf[n], acc[m][n], 0, 0, 0);
    }
#undef STAGE

    const long coff = (long)z * cH;
    if constexpr (EPI == 3) {
#pragma unroll
        for (int m = 0; m < 4; ++m) {
            const int row0 = tm + wr + m * 16 + fk * 4;
#pragma unroll
            for (int np = 0; np < 4; np += 2) {
                const int col = ((tn + wc + np * 16) >> 5) * 16 + frow;
                f32x4 av = acc[m][np], gv = acc[m][np + 1];
#pragma unroll
                for (int r = 0; r < 4; ++r) {
                    const float g = gv[r];
                    const float o = av[r] * g / (1.0f + __expf(-g));
                    ((u16*)Cv)[(long)(row0 + r) * ldc + col] = f2b(o);
                }
            }
        }
    } else {
#pragma unroll
        for (int m = 0; m < 4; ++m) {
            const int row0 = tm + wr + m * 16 + fk * 4;
#pragma unroll
            for (int n = 0; n < 4; ++n) {
                const int col = tn + wc + n * 16 + frow;
#pragma unroll
                for (int r = 0; r < 4; ++r) {
                    const long off = coff + (long)(row0 + r) * ldc + col;
                    const float v = acc[m][n][r];
                    if constexpr (EPI == 0)      ((u16*)Cv)[off] = f2b(v);
                    else if constexpr (EPI == 1) ((float*)Cv)[off] = v;
                    else if constexpr (EPI == 2) ((float*)Cv)[off] += v;
                    else                         atomicAdd(&((float*)Cv)[off], v);
                }
            }
        }
    }
}

// ---------------------------------------------------------------------------
// Flash attention. Grid (16 qtiles, 16 heads, 2 batches), 256 thr = 4 waves.
// Swapped QK^T: S^T[j][q] via mfma(A=Kext row-frag, B=Q row-frag). Each wave
// owns 32 q-cols (full 128-j tile). Mask folded into Kext col 64 (bias).
// P staged per-wave in LDS [32 q][128 j] with 16B-unit XOR swizzle keyed by
// (q&7). O^T = V^T @ P^T accumulated in regs; written /l as bf16 in
// head-interleaved [b][q][h*64+d] layout (Wout GEMM A-operand).
// ---------------------------------------------------------------------------
__global__ __launch_bounds__(256, 2)
void flash_attn(const u16* __restrict__ qb, const u16* __restrict__ kext,
                const u16* __restrict__ vT, u16* __restrict__ aout)
{
    __shared__ __align__(16) u16 PL[4 * 32 * 128];
    const int tid  = threadIdx.x;
    const int wave = tid >> 6, lane = tid & 63;
    const int frow = lane & 15, fk = lane >> 4;
    const int b = blockIdx.z, h = blockIdx.y;
    const int q0 = blockIdx.x * 128;

    // Q B-frags (reused all 16 j-tiles): bq[n][kk], qcol = n*16+frow, d = kk*32+fk*8
    const u16* qbase = qb + ((long)(b * 2048 + q0 + wave * 32)) * 1024 + h * 64;
    bf16x8 bq[2][2];
#pragma unroll
    for (int n = 0; n < 2; ++n)
#pragma unroll
        for (int kk = 0; kk < 2; ++kk)
            bq[n][kk] = *(const bf16x8*)&qbase[(long)(n * 16 + frow) * 1024 + kk * 32 + fk * 8];
    // bias B-frag: B[k=64+fk*8+jj][*] = (k==64) ? 1 : 0
    u16x8 tz = {0, 0, 0, 0, 0, 0, 0, 0};
    if (fk == 0) tz[0] = 0x3F80;
    const bf16x8 bqe = __builtin_bit_cast(bf16x8, tz);

    const u16* kbase = kext + (long)b * 2048 * 96;
    const u16* vbase = vT   + (long)b * 64 * 2048;
    u16* plw = &PL[wave * 32 * 128];
    const int swz = frow & 7;

    f32x4 oacc[4][2] = {};
    float mrun[2] = {-1e30f, -1e30f};
    float lrun[2] = {0.0f, 0.0f};

    for (int it = 0; it < 16; ++it) {
        const int j0 = it * 128;
        f32x4 st[8][2] = {};
        // --- S^T = Kext @ Q^T (ksteps 0,1 real d; kstep 2 = mask bias) ---
#pragma unroll
        for (int kk = 0; kk < 3; ++kk) {
            bf16x8 ka[8];
#pragma unroll
            for (int m = 0; m < 8; ++m)
                ka[m] = *(const bf16x8*)&kbase[(long)(j0 + m * 16 + frow) * 96 + kk * 32 + fk * 8];
#pragma unroll
            for (int m = 0; m < 8; ++m) {
                st[m][0] = __builtin_amdgcn_mfma_f32_16x16x32_bf16(ka[m], kk < 2 ? bq[0][kk] : bqe, st[m][0], 0, 0, 0);
                st[m][1] = __builtin_amdgcn_mfma_f32_16x16x32_bf16(ka[m], kk < 2 ? bq[1][kk] : bqe, st[m][1], 0, 0, 0);
            }
        }
        // --- online softmax over j (rows of S^T) per q-col ---
        float alpha[2];
#pragma unroll
        for (int n = 0; n < 2; ++n) {
            float pm = st[0][n][0];
#pragma unroll
            for (int m = 0; m < 8; ++m)
#pragma unroll
                for (int r = 0; r < 4; ++r) pm = fmaxf(pm, st[m][n][r]);
            pm = fmaxf(pm, __shfl_xor(pm, 16));
            pm = fmaxf(pm, __shfl_xor(pm, 32));
            const float nm = fmaxf(mrun[n], pm);
            alpha[n] = __expf(mrun[n] - nm);
            mrun[n] = nm;
        }
        float rs[2] = {0.0f, 0.0f};
#pragma unroll
        for (int m = 0; m < 8; ++m) {
            const int j = m * 16 + fk * 4;
            const u32 eladdr = (((j >> 3) ^ swz) * 8) + (j & 7);
#pragma unroll
            for (int n = 0; n < 2; ++n) {
                const float p0 = __expf(st[m][n][0] - mrun[n]);
                const float p1 = __expf(st[m][n][1] - mrun[n]);
                const float p2 = __expf(st[m][n][2] - mrun[n]);
                const float p3 = __expf(st[m][n][3] - mrun[n]);
                rs[n] += (p0 + p1) + (p2 + p3);
                uint2 w; w.x = pack2(p0, p1); w.y = pack2(p2, p3);
                *(uint2*)&plw[(u32)(n * 16 + frow) * 128 + eladdr] = w;
            }
        }
#pragma unroll
        for (int n = 0; n < 2; ++n) {
            rs[n] += __shfl_xor(rs[n], 16);
            rs[n] += __shfl_xor(rs[n], 32);
            lrun[n] = lrun[n] * alpha[n] + rs[n];
        }
#pragma unroll
        for (int mo = 0; mo < 4; ++mo)
#pragma unroll
            for (int no = 0; no < 2; ++no)
#pragma unroll
                for (int r = 0; r < 4; ++r) oacc[mo][no][r] *= alpha[no];
        // --- O^T += V^T @ P^T ---
#pragma unroll
        for (int kkv = 0; kkv < 4; ++kkv) {
            bf16x8 va[4], pb[2];
#pragma unroll
            for (int mo = 0; mo < 4; ++mo)
                va[mo] = *(const bf16x8*)&vbase[(long)(mo * 16 + frow) * 2048 + j0 + kkv * 32 + fk * 8];
            const int jj = kkv * 32 + fk * 8;
            const u32 rdoff = ((jj >> 3) ^ swz) * 8;
#pragma unroll
            for (int no = 0; no < 2; ++no)
                pb[no] = *(const bf16x8*)&plw[(u32)(no * 16 + frow) * 128 + rdoff];
#pragma unroll
            for (int mo = 0; mo < 4; ++mo)
#pragma unroll
                for (int no = 0; no < 2; ++no)
                    oacc[mo][no] = __builtin_amdgcn_mfma_f32_16x16x32_bf16(va[mo], pb[no], oacc[mo][no], 0, 0, 0);
        }
    }
    // --- epilogue: O / l, bf16, head-interleaved write ---
#pragma unroll
    for (int no = 0; no < 2; ++no) {
        const float inv = 1.0f / lrun[no];
        const long row = (long)b * 2048 + q0 + wave * 32 + no * 16 + frow;
#pragma unroll
        for (int mo = 0; mo < 4; ++mo) {
            uint2 w;
            w.x = pack2(oacc[mo][no][0] * inv, oacc[mo][no][1] * inv);
            w.y = pack2(oacc[mo][no][2] * inv, oacc[mo][no][3] * inv);
            *(uint2*)&aout[row * 1024 + h * 64 + mo * 16 + fk * 4] = w;
        }
    }
}

// ---------------------------------------------------------------------------
extern "C" void kernel_launch(void* const* d_in, const int* in_sizes, int n_in,
                              void* d_out, int out_size, void* d_ws, size_t ws_size,
                              hipStream_t stream)
{
    const float* x      = (const float*)d_in[0];
    const float* ctx    = (const float*)d_in[1];
    const int*   mask   = (const int*)d_in[2];
    const float* gamma  = (const float*)d_in[3];
    const float* cgamma = (const float*)d_in[4];
    const float* Wq     = (const float*)d_in[5];
    const float* Wkv    = (const float*)d_in[6];
    const float* Wout   = (const float*)d_in[7];
    const float* Wff1   = (const float*)d_in[8];
    const float* Wff2   = (const float*)d_in[9];
    float* out = (float*)d_out;

    char* w = (char*)d_ws;
    auto carveB = [&](long bytes) { char* p = w; w += ((bytes + 255) / 256) * 256; return p; };
    u16*   xn     = (u16*)  carveB(4096L * 1024 * 2);
    u16*   ctxn   = (u16*)  carveB(4096L * 1024 * 2);
    u16*   WqT    = (u16*)  carveB(1024L * 1024 * 2);
    u16*   WkvT   = (u16*)  carveB(128L * 1024 * 2);
    u16*   WoutT  = (u16*)  carveB(1024L * 1024 * 2);
    u16*   Wff1Tp = (u16*)  carveB(8192L * 1024 * 2);
    u16*   Wff2T  = (u16*)  carveB(1024L * 4096 * 2);
    u16*   q      = (u16*)  carveB(4096L * 1024 * 2);
    float* kvf    = (float*)carveB(2L * 2048 * 128 * 4);
    u16*   kext   = (u16*)  carveB(2L * 2048 * 96 * 2);
    u16*   vT     = (u16*)  carveB(2L * 64 * 2048 * 2);
    u16*   aout   = (u16*)  carveB(4096L * 1024 * 2);
    u16*   gbuf   = (u16*)  carveB(4096L * 4096 * 2);

    dim3 B(256);

    ln_kernel<<<dim3(8192), B, 0, stream>>>(x, ctx, gamma, cgamma, xn, ctxn);
    wconv<<<dim3(32, 32),  B, 0, stream>>>(Wq,   WqT,   1024, 1024, 0.125f);  // q scale folded
    wconv<<<dim3(4, 32),   B, 0, stream>>>(Wkv,  WkvT,  128,  1024, 1.0f);
    wconv<<<dim3(32, 32),  B, 0, stream>>>(Wout, WoutT, 1024, 1024, 1.0f);
    wconv_ff1<<<dim3(256, 32), B, 0, stream>>>(Wff1, Wff1Tp);
    wconv<<<dim3(32, 128), B, 0, stream>>>(Wff2, Wff2T, 1024, 4096, 1.0f);

    // q = xn @ WqT^T : M=4096 N=1024 K=1024
    gemm_bt<0><<<dim3(8, 32, 1), B, 0, stream>>>(xn, WqT, q, 1024, 1024, 1024, 1024, 0, 0, 0);
    // kvf = ctxn @ WkvT^T (f32, split-K x4 atomic): M=4096 N=128 K=1024
    hipMemsetAsync(kvf, 0, 2L * 2048 * 128 * 4, stream);
    gemm_bt<4><<<dim3(1, 32, 4), B, 0, stream>>>(ctxn, WkvT, kvf, 256, 1024, 1024, 128, 256, 256, 0);
    kext_build<<<dim3(192), B, 0, stream>>>(kvf, mask, kext);
    vtrans<<<dim3(8, 64, 2), B, 0, stream>>>(kvf, vT);

    // fused attention -> aout [b][q][h*64+d]
    flash_attn<<<dim3(16, 16, 2), B, 0, stream>>>(q, kext, vT, aout);

    // out = aout @ WoutT^T (f32 write)
    gemm_bt<1><<<dim3(8, 32, 1), B, 0, stream>>>(aout, WoutT, out, 1024, 1024, 1024, 1024, 0, 0, 0);
    // gbuf = swiglu(xn @ Wff1Tp^T) : N=8192 -> 4096 silu cols
    gemm_bt<3><<<dim3(64, 32, 1), B, 0, stream>>>(xn, Wff1Tp, gbuf, 1024, 1024, 1024, 4096, 0, 0, 0);
    // out += gbuf @ Wff2T^T : K=4096 (f32 accumulate)
    gemm_bt<2><<<dim3(8, 32, 1), B, 0, stream>>>(gbuf, Wff2T, out, 4096, 4096, 4096, 1024, 0, 0, 0);
}

// Round 3
// 425.002 us; speedup vs baseline: 1.3685x; 1.1659x over previous
//
#include <hip/hip_runtime.h>

typedef unsigned short u16;
typedef unsigned int   u32;
typedef __bf16  bf16x8 __attribute__((ext_vector_type(8)));
typedef __bf16  bf16x2 __attribute__((ext_vector_type(2)));
typedef float   f32x4  __attribute__((ext_vector_type(4)));

static __device__ __forceinline__ float b2f(u16 v) {
    return __builtin_bit_cast(float, (u32)(((u32)v) << 16));
}
static __device__ __forceinline__ u16 f2b(float f) {  // RNE f32->bf16
    u32 u = __builtin_bit_cast(u32, f);
    return (u16)((u + 0x7FFFu + ((u >> 16) & 1u)) >> 16);
}
static __device__ __forceinline__ u32 pack2(float a, float b) {
    bf16x2 t; t[0] = (__bf16)a; t[1] = (__bf16)b;
    return __builtin_bit_cast(u32, t);
}

// ---------------------------------------------------------------------------
// LayerNorm: rows 0..4095 = x, 4096..8191 = context. 1024 f32 per row.
// ---------------------------------------------------------------------------
__global__ __launch_bounds__(256)
void ln_kernel(const float* __restrict__ x, const float* __restrict__ ctx,
               const float* __restrict__ gamma, const float* __restrict__ cgamma,
               u16* __restrict__ xn, u16* __restrict__ ctxn)
{
    const int row = blockIdx.x;
    const int tid = threadIdx.x;
    const float* src; const float* g; u16* dst;
    if (row < 4096) { src = x   + (long)row * 1024;          g = gamma;  dst = xn   + (long)row * 1024; }
    else            { src = ctx + (long)(row - 4096) * 1024; g = cgamma; dst = ctxn + (long)(row - 4096) * 1024; }
    float4 v = ((const float4*)src)[tid];
    float s = v.x + v.y + v.z + v.w;
    float q = v.x*v.x + v.y*v.y + v.z*v.z + v.w*v.w;
#pragma unroll
    for (int off = 32; off; off >>= 1) { s += __shfl_xor(s, off); q += __shfl_xor(q, off); }
    __shared__ float r1[4], r2[4];
    if ((tid & 63) == 0) { r1[tid >> 6] = s; r2[tid >> 6] = q; }
    __syncthreads();
    s = r1[0] + r1[1] + r1[2] + r1[3];
    q = r2[0] + r2[1] + r2[2] + r2[3];
    float mu   = s * (1.0f / 1024.0f);
    float var  = q * (1.0f / 1024.0f) - mu * mu;
    float rstd = rsqrtf(var + 1e-5f);
    float4 gv = ((const float4*)g)[tid];
    ushort4 o;
    o.x = f2b((v.x - mu) * rstd * gv.x);
    o.y = f2b((v.y - mu) * rstd * gv.y);
    o.z = f2b((v.z - mu) * rstd * gv.z);
    o.w = f2b((v.w - mu) * rstd * gv.w);
    ((ushort4*)dst)[tid] = o;
}

// ---------------------------------------------------------------------------
// Weight convert: W f32 [K][N] row-major -> Wt bf16 [N][K] row-major, *scale
// ---------------------------------------------------------------------------
__global__ __launch_bounds__(256)
void wconv(const float* __restrict__ W, u16* __restrict__ Wt, int N, int K, float scale)
{
    __shared__ float tile[32][33];
    const int tid = threadIdx.x;
    const int n0 = blockIdx.x * 32;
    const int k0 = blockIdx.y * 32;
    const int r  = tid >> 3;
    const int c4 = (tid & 7) * 4;
    float4 v = *(const float4*)&W[(long)(k0 + r) * N + n0 + c4];
    tile[r][c4 + 0] = v.x; tile[r][c4 + 1] = v.y; tile[r][c4 + 2] = v.z; tile[r][c4 + 3] = v.w;
    __syncthreads();
    ushort4 o;
    o.x = f2b(tile[c4 + 0][r] * scale);
    o.y = f2b(tile[c4 + 1][r] * scale);
    o.z = f2b(tile[c4 + 2][r] * scale);
    o.w = f2b(tile[c4 + 3][r] * scale);
    *(ushort4*)&Wt[(long)(n0 + r) * K + k0 + c4] = o;
}

// ---------------------------------------------------------------------------
// Wff1 convert with a/gate interleave: phys row p <- logical col
// L(p) = (p&16 ? 4096:0) + (p>>5)*16 + (p&15).
// ---------------------------------------------------------------------------
__global__ __launch_bounds__(256)
void wconv_ff1(const float* __restrict__ W, u16* __restrict__ Wt)
{
    __shared__ float tile[32][33];
    const int tid = threadIdx.x;
    const int a  = blockIdx.x;            // 0..255
    const int k0 = blockIdx.y * 32;
    const int r  = tid >> 3;
    const int c4 = (tid & 7) * 4;
    const int srccol = (c4 < 16) ? (a * 16 + c4) : (4096 + a * 16 + (c4 - 16));
    float4 v = *(const float4*)&W[(long)(k0 + r) * 8192 + srccol];
    tile[r][c4 + 0] = v.x; tile[r][c4 + 1] = v.y; tile[r][c4 + 2] = v.z; tile[r][c4 + 3] = v.w;
    __syncthreads();
    ushort4 o;
    o.x = f2b(tile[c4 + 0][r]);
    o.y = f2b(tile[c4 + 1][r]);
    o.z = f2b(tile[c4 + 2][r]);
    o.w = f2b(tile[c4 + 3][r]);
    *(ushort4*)&Wt[(long)(a * 32 + r) * 1024 + k0 + c4] = o;
}

// ---------------------------------------------------------------------------
// kext: [2][2048][64] bf16 K rows; mbias [2][2048] f32 = 0 or -1e30.
// ---------------------------------------------------------------------------
__global__ __launch_bounds__(256)
void kext_build(const float* __restrict__ kvf, const int* __restrict__ mask,
                u16* __restrict__ kext, float* __restrict__ mbias)
{
    const int gid = blockIdx.x * 256 + threadIdx.x;   // 2*2048*8 = 32768
    const int b = gid >> 14;
    const int rem = gid & 16383;
    const int j = rem >> 3;
    const int c = rem & 7;
    const float* src = &kvf[((long)b * 2048 + j) * 128 + c * 8];
    u16 ov[8];
#pragma unroll
    for (int e = 0; e < 8; ++e) ov[e] = f2b(src[e]);
    uint4 w;
    w.x = (u32)ov[0] | ((u32)ov[1] << 16);
    w.y = (u32)ov[2] | ((u32)ov[3] << 16);
    w.z = (u32)ov[4] | ((u32)ov[5] << 16);
    w.w = (u32)ov[6] | ((u32)ov[7] << 16);
    *(uint4*)&kext[((long)b * 2048 + j) * 64 + c * 8] = w;
    if (c == 0) mbias[b * 2048 + j] = mask[b * 2048 + j] ? 0.0f : -1e30f;
}

// ---------------------------------------------------------------------------
// vT [2][64][2048] bf16 <- V columns of kvf f32 [2][2048][128]
// ---------------------------------------------------------------------------
__global__ __launch_bounds__(256)
void vtrans(const float* __restrict__ kvf, u16* __restrict__ vT)
{
    const int j = blockIdx.x * 256 + threadIdx.x;
    const int d = blockIdx.y;
    const int b = blockIdx.z;
    vT[(long)b * 64 * 2048 + (long)d * 2048 + j] =
        f2b(kvf[((long)b * 2048 + j) * 128 + 64 + d]);
}

// ---------------------------------------------------------------------------
// GEMM: C[M][N] = A[M][K](bf16) @ Bt[N][K](bf16)^T.  128x128 tile, BK=32.
// EPI: 0 bf16-store, 1 f32-store, 2 f32-accumulate, 3 swiglu, 4 f32 atomic.
// XCD chunk swizzle (bijective, nwg%8==0 for all our grids).
// ---------------------------------------------------------------------------
#define BM 128
#define BN 128
#define BK 32

template<int EPI>
__global__ __launch_bounds__(256, 2)
void gemm_bt(const u16* __restrict__ A, const u16* __restrict__ Bt,
             void* __restrict__ Cv,
             int K, int lda, int ldb, int ldc,
             long aH, long bH, long cH)
{
    __shared__ __align__(16) u16 sm[2][2][BM * BK];
    const int tid  = threadIdx.x;
    const int wave = tid >> 6;
    const int lane = tid & 63;
    // XCD-aware chunk swizzle on the (x,y)-flattened index
    const int gx = gridDim.x;
    const int nwg = gx * gridDim.y;
    int wg = blockIdx.y * gx + blockIdx.x;
    if ((nwg & 7) == 0 && nwg >= 16)
        wg = (wg & 7) * (nwg >> 3) + (wg >> 3);
    const int tn = (wg % gx) * BN;
    const int tm = (wg / gx) * BM;
    const int z  = blockIdx.z;
    A  += (long)z * aH;
    Bt += (long)z * bH;

    const int arow0 = (tid >> 2);
    const int arow1 = 64 + (tid >> 2);
    const int acs0  = (tid & 3) ^ ((arow0 >> 1) & 3);
    const int acs1  = (tid & 3) ^ ((arow1 >> 1) & 3);
    const int nt = K / BK;

#define STAGE(buf, k0)                                                                              \
    do {                                                                                            \
        __builtin_amdgcn_global_load_lds(                                                           \
            (const __attribute__((address_space(1))) void*)(A + (long)(tm + arow0) * lda + (k0) + acs0 * 8),   \
            (__attribute__((address_space(3))) void*)(&sm[buf][0][(wave * 64) * 8]), 16, 0, 0);     \
        __builtin_amdgcn_global_load_lds(                                                           \
            (const __attribute__((address_space(1))) void*)(A + (long)(tm + arow1) * lda + (k0) + acs1 * 8),   \
            (__attribute__((address_space(3))) void*)(&sm[buf][0][(256 + wave * 64) * 8]), 16, 0, 0); \
        __builtin_amdgcn_global_load_lds(                                                           \
            (const __attribute__((address_space(1))) void*)(Bt + (long)(tn + arow0) * ldb + (k0) + acs0 * 8),  \
            (__attribute__((address_space(3))) void*)(&sm[buf][1][(wave * 64) * 8]), 16, 0, 0);     \
        __builtin_amdgcn_global_load_lds(                                                           \
            (const __attribute__((address_space(1))) void*)(Bt + (long)(tn + arow1) * ldb + (k0) + acs1 * 8),  \
            (__attribute__((address_space(3))) void*)(&sm[buf][1][(256 + wave * 64) * 8]), 16, 0, 0); \
    } while (0)

    STAGE(0, 0);

    f32x4 acc[4][4] = {};
    const int wr   = (wave >> 1) * 64;
    const int wc   = (wave & 1) * 64;
    const int frow = lane & 15;
    const int fk   = lane >> 4;

    for (int t = 0; t < nt; ++t) {
        __syncthreads();
        if (t + 1 < nt) STAGE((t + 1) & 1, (t + 1) * BK);
        const int cur = t & 1;
        bf16x8 af[4], bf[4];
#pragma unroll
        for (int m = 0; m < 4; ++m) {
            int row = wr + m * 16 + frow;
            af[m] = *(const bf16x8*)&sm[cur][0][row * BK + ((fk ^ ((row >> 1) & 3)) * 8)];
        }
#pragma unroll
        for (int n = 0; n < 4; ++n) {
            int row = wc + n * 16 + frow;
            bf[n] = *(const bf16x8*)&sm[cur][1][row * BK + ((fk ^ ((row >> 1) & 3)) * 8)];
        }
#pragma unroll
        for (int m = 0; m < 4; ++m)
#pragma unroll
            for (int n = 0; n < 4; ++n)
                acc[m][n] = __builtin_amdgcn_mfma_f32_16x16x32_bf16(af[m], bf[n], acc[m][n], 0, 0, 0);
    }
#undef STAGE

    const long coff = (long)z * cH;
    if constexpr (EPI == 3) {
#pragma unroll
        for (int m = 0; m < 4; ++m) {
            const int row0 = tm + wr + m * 16 + fk * 4;
#pragma unroll
            for (int np = 0; np < 4; np += 2) {
                const int col = ((tn + wc + np * 16) >> 5) * 16 + frow;
                f32x4 av = acc[m][np], gv = acc[m][np + 1];
#pragma unroll
                for (int r = 0; r < 4; ++r) {
                    const float g = gv[r];
                    const float o = av[r] * g / (1.0f + __expf(-g));
                    ((u16*)Cv)[(long)(row0 + r) * ldc + col] = f2b(o);
                }
            }
        }
    } else {
#pragma unroll
        for (int m = 0; m < 4; ++m) {
            const int row0 = tm + wr + m * 16 + fk * 4;
#pragma unroll
            for (int n = 0; n < 4; ++n) {
                const int col = tn + wc + n * 16 + frow;
#pragma unroll
                for (int r = 0; r < 4; ++r) {
                    const long off = coff + (long)(row0 + r) * ldc + col;
                    const float v = acc[m][n][r];
                    if constexpr (EPI == 0)      ((u16*)Cv)[off] = f2b(v);
                    else if constexpr (EPI == 1) ((float*)Cv)[off] = v;
                    else if constexpr (EPI == 2) ((float*)Cv)[off] += v;
                    else                         atomicAdd(&((float*)Cv)[off], v);
                }
            }
        }
    }
}

// ---------------------------------------------------------------------------
// Flash attention v2. Grid (32 qtiles, 16 heads, 2 batches), 256 thr = 4
// waves; QBLK=64 (16 q/wave), JBLK=64. K/V staged via global_load_lds into
// double-buffered LDS shared by all waves (read-swizzle pre-applied on the
// global source). Mask = f32 bias added by VALU. P per-wave in swizzled LDS.
// LDS = 16+16+8 = 40KB -> 4 blocks/CU, 4 waves/SIMD.
// ---------------------------------------------------------------------------
__global__ __launch_bounds__(256, 4)
void flash_attn(const u16* __restrict__ qb, const u16* __restrict__ kext,
                const u16* __restrict__ vT, const float* __restrict__ mbias,
                u16* __restrict__ aout)
{
    __shared__ __align__(16) u16 Ksm[2][4096];   // [64 j][64 d], chunk-swizzled
    __shared__ __align__(16) u16 Vsm[2][4096];   // [64 d][64 j], chunk-swizzled
    __shared__ __align__(16) u16 Psm[4][1024];   // per-wave [16 q][64 j], swz
    const int tid  = threadIdx.x;
    const int wave = tid >> 6, lane = tid & 63;
    const int frow = lane & 15, fk = lane >> 4;
    const int b = blockIdx.z, h = blockIdx.y;
    const int q0 = blockIdx.x * 64;

    const u16* kx = kext + (long)b * 2048 * 64;
    const u16* vb = vT   + (long)b * 64 * 2048;
    const float* mbb = mbias + b * 2048;

    // Q B-frags (persist): col q = frow (within wave's 16 q), k = kk*32+fk*8
    const u16* qbase = qb + ((long)(b * 2048 + q0 + wave * 16 + frow)) * 1024 + h * 64;
    bf16x8 bq[2];
#pragma unroll
    for (int kk = 0; kk < 2; ++kk)
        bq[kk] = *(const bf16x8*)&qbase[kk * 32 + fk * 8];

    // staging: slot s = i*256+tid; row=s>>3, cphys=s&7, csrc=cphys^(row&7)
#define FSTAGE(buf, j0s)                                                                             \
    do {                                                                                             \
        _Pragma("unroll")                                                                            \
        for (int i = 0; i < 2; ++i) {                                                                \
            const int slot = i * 256 + tid;                                                          \
            const int row  = slot >> 3;                                                              \
            const int csrc = (slot & 7) ^ (row & 7);                                                 \
            __builtin_amdgcn_global_load_lds(                                                        \
                (const __attribute__((address_space(1))) void*)(kx + (long)((j0s) + row) * 64 + csrc * 8), \
                (__attribute__((address_space(3))) void*)(&Ksm[buf][(i * 256 + wave * 64) * 8]), 16, 0, 0); \
            __builtin_amdgcn_global_load_lds(                                                        \
                (const __attribute__((address_space(1))) void*)(vb + (long)row * 2048 + (j0s) + csrc * 8),  \
                (__attribute__((address_space(3))) void*)(&Vsm[buf][(i * 256 + wave * 64) * 8]), 16, 0, 0); \
        }                                                                                            \
    } while (0)

    FSTAGE(0, 0);

    f32x4 oacc[4] = {};
    float mrun = -1e30f, lrun = 0.0f;
    u16* pw = &Psm[wave][0];

    for (int it = 0; it < 32; ++it) {
        const int j0 = it * 64;
        __syncthreads();                       // buf[cur] staged for all waves
        // mask bias prefetch (before next-stage issue keeps its wait shallow)
        float4 mb[4];
#pragma unroll
        for (int m = 0; m < 4; ++m)
            mb[m] = *(const float4*)&mbb[j0 + m * 16 + fk * 4];
        if (it + 1 < 32) FSTAGE((it + 1) & 1, (it + 1) * 64);
        const int cur = it & 1;

        // --- S^T = K @ Q^T : st[m][r] -> j = m*16+fk*4+r, q = frow ---
        f32x4 st[4] = {};
        __builtin_amdgcn_s_setprio(1);
#pragma unroll
        for (int kk = 0; kk < 2; ++kk) {
            bf16x8 ka[4];
#pragma unroll
            for (int m = 0; m < 4; ++m) {
                const int row = m * 16 + frow;
                ka[m] = *(const bf16x8*)&Ksm[cur][row * 64 + (((kk * 4 + fk) ^ (row & 7)) * 8)];
            }
#pragma unroll
            for (int m = 0; m < 4; ++m)
                st[m] = __builtin_amdgcn_mfma_f32_16x16x32_bf16(ka[m], bq[kk], st[m], 0, 0, 0);
        }
        __builtin_amdgcn_s_setprio(0);

        // --- biased scores, online softmax ---
        float sb[4][4];
#pragma unroll
        for (int m = 0; m < 4; ++m)
#pragma unroll
            for (int r = 0; r < 4; ++r) sb[m][r] = st[m][r] + (&mb[m].x)[r];
        float pm = fmaxf(
            fmaxf(fmaxf(sb[0][0], sb[0][1]), fmaxf(sb[0][2], sb[0][3])),
            fmaxf(fmaxf(sb[1][0], sb[1][1]), fmaxf(sb[1][2], sb[1][3])));
        pm = fmaxf(pm, fmaxf(
            fmaxf(fmaxf(sb[2][0], sb[2][1]), fmaxf(sb[2][2], sb[2][3])),
            fmaxf(fmaxf(sb[3][0], sb[3][1]), fmaxf(sb[3][2], sb[3][3]))));
        pm = fmaxf(pm, __shfl_xor(pm, 16));
        pm = fmaxf(pm, __shfl_xor(pm, 32));
        const float nm = fmaxf(mrun, pm);
        const float alpha = __expf(mrun - nm);
        mrun = nm;

        float rs = 0.0f;
#pragma unroll
        for (int m = 0; m < 4; ++m) {
            const float p0 = __expf(sb[m][0] - nm);
            const float p1 = __expf(sb[m][1] - nm);
            const float p2 = __expf(sb[m][2] - nm);
            const float p3 = __expf(sb[m][3] - nm);
            rs += (p0 + p1) + (p2 + p3);
            const int chunk = (m * 2 + (fk >> 1)) ^ (frow & 7);
            uint2 w; w.x = pack2(p0, p1); w.y = pack2(p2, p3);
            *(uint2*)&pw[frow * 64 + chunk * 8 + (fk & 1) * 4] = w;
        }
        rs += __shfl_xor(rs, 16);
        rs += __shfl_xor(rs, 32);
        lrun = lrun * alpha + rs;
#pragma unroll
        for (int mo = 0; mo < 4; ++mo)
#pragma unroll
            for (int r = 0; r < 4; ++r) oacc[mo][r] *= alpha;

        // --- O^T += V^T @ P^T ---
        __builtin_amdgcn_s_setprio(1);
#pragma unroll
        for (int kkv = 0; kkv < 2; ++kkv) {
            bf16x8 va[4];
#pragma unroll
            for (int mo = 0; mo < 4; ++mo) {
                const int row = mo * 16 + frow;
                va[mo] = *(const bf16x8*)&Vsm[cur][row * 64 + (((kkv * 4 + fk) ^ (row & 7)) * 8)];
            }
            const bf16x8 pb = *(const bf16x8*)&pw[frow * 64 + (((kkv * 4 + fk) ^ (frow & 7)) * 8)];
#pragma unroll
            for (int mo = 0; mo < 4; ++mo)
                oacc[mo] = __builtin_amdgcn_mfma_f32_16x16x32_bf16(va[mo], pb, oacc[mo], 0, 0, 0);
        }
        __builtin_amdgcn_s_setprio(0);
    }
#undef FSTAGE

    // --- epilogue: O / l, head-interleaved bf16 write ---
    const float inv = 1.0f / lrun;
    const long row = (long)b * 2048 + q0 + wave * 16 + frow;
#pragma unroll
    for (int mo = 0; mo < 4; ++mo) {
        uint2 w;
        w.x = pack2(oacc[mo][0] * inv, oacc[mo][1] * inv);
        w.y = pack2(oacc[mo][2] * inv, oacc[mo][3] * inv);
        *(uint2*)&aout[row * 1024 + h * 64 + mo * 16 + fk * 4] = w;
    }
}

// ---------------------------------------------------------------------------
extern "C" void kernel_launch(void* const* d_in, const int* in_sizes, int n_in,
                              void* d_out, int out_size, void* d_ws, size_t ws_size,
                              hipStream_t stream)
{
    const float* x      = (const float*)d_in[0];
    const float* ctx    = (const float*)d_in[1];
    const int*   mask   = (const int*)d_in[2];
    const float* gamma  = (const float*)d_in[3];
    const float* cgamma = (const float*)d_in[4];
    const float* Wq     = (const float*)d_in[5];
    const float* Wkv    = (const float*)d_in[6];
    const float* Wout   = (const float*)d_in[7];
    const float* Wff1   = (const float*)d_in[8];
    const float* Wff2   = (const float*)d_in[9];
    float* out = (float*)d_out;

    char* w = (char*)d_ws;
    auto carveB = [&](long bytes) { char* p = w; w += ((bytes + 255) / 256) * 256; return p; };
    u16*   xn     = (u16*)  carveB(4096L * 1024 * 2);
    u16*   ctxn   = (u16*)  carveB(4096L * 1024 * 2);
    u16*   WqT    = (u16*)  carveB(1024L * 1024 * 2);
    u16*   WkvT   = (u16*)  carveB(128L * 1024 * 2);
    u16*   WoutT  = (u16*)  carveB(1024L * 1024 * 2);
    u16*   Wff1Tp = (u16*)  carveB(8192L * 1024 * 2);
    u16*   Wff2T  = (u16*)  carveB(1024L * 4096 * 2);
    u16*   q      = (u16*)  carveB(4096L * 1024 * 2);
    float* kvf    = (float*)carveB(2L * 2048 * 128 * 4);
    u16*   kext   = (u16*)  carveB(2L * 2048 * 64 * 2);
    float* mbias  = (float*)carveB(2L * 2048 * 4);
    u16*   vT     = (u16*)  carveB(2L * 64 * 2048 * 2);
    u16*   aout   = (u16*)  carveB(4096L * 1024 * 2);
    u16*   gbuf   = (u16*)  carveB(4096L * 4096 * 2);

    dim3 B(256);

    ln_kernel<<<dim3(8192), B, 0, stream>>>(x, ctx, gamma, cgamma, xn, ctxn);
    wconv<<<dim3(32, 32),  B, 0, stream>>>(Wq,   WqT,   1024, 1024, 0.125f);  // q scale folded
    wconv<<<dim3(4, 32),   B, 0, stream>>>(Wkv,  WkvT,  128,  1024, 1.0f);
    wconv<<<dim3(32, 32),  B, 0, stream>>>(Wout, WoutT, 1024, 1024, 1.0f);
    wconv_ff1<<<dim3(256, 32), B, 0, stream>>>(Wff1, Wff1Tp);
    wconv<<<dim3(32, 128), B, 0, stream>>>(Wff2, Wff2T, 1024, 4096, 1.0f);

    // q = xn @ WqT^T : M=4096 N=1024 K=1024
    gemm_bt<0><<<dim3(8, 32, 1), B, 0, stream>>>(xn, WqT, q, 1024, 1024, 1024, 1024, 0, 0, 0);
    // kvf = ctxn @ WkvT^T (f32, split-K x4 atomic): M=4096 N=128 K=1024
    hipMemsetAsync(kvf, 0, 2L * 2048 * 128 * 4, stream);
    gemm_bt<4><<<dim3(1, 32, 4), B, 0, stream>>>(ctxn, WkvT, kvf, 256, 1024, 1024, 128, 256, 256, 0);
    kext_build<<<dim3(128), B, 0, stream>>>(kvf, mask, kext, mbias);
    vtrans<<<dim3(8, 64, 2), B, 0, stream>>>(kvf, vT);

    // fused attention -> aout [b][q][h*64+d]
    flash_attn<<<dim3(32, 16, 2), B, 0, stream>>>(q, kext, vT, mbias, aout);

    // out = aout @ WoutT^T (f32 write)
    gemm_bt<1><<<dim3(8, 32, 1), B, 0, stream>>>(aout, WoutT, out, 1024, 1024, 1024, 1024, 0, 0, 0);
    // gbuf = swiglu(xn @ Wff1Tp^T) : N=8192 -> 4096 silu cols
    gemm_bt<3><<<dim3(64, 32, 1), B, 0, stream>>>(xn, Wff1Tp, gbuf, 1024, 1024, 1024, 4096, 0, 0, 0);
    // out += gbuf @ Wff2T^T : K=4096 (f32 accumulate)
    gemm_bt<2><<<dim3(8, 32, 1), B, 0, stream>>>(gbuf, Wff2T, out, 4096, 4096, 4096, 1024, 0, 0, 0);
}

// Round 4
// 417.059 us; speedup vs baseline: 1.3945x; 1.0190x over previous
//
#include <hip/hip_runtime.h>

typedef unsigned short u16;
typedef unsigned int   u32;
typedef __bf16  bf16x8 __attribute__((ext_vector_type(8)));
typedef __bf16  bf16x2 __attribute__((ext_vector_type(2)));
typedef float   f32x4  __attribute__((ext_vector_type(4)));

static __device__ __forceinline__ float b2f(u16 v) {
    return __builtin_bit_cast(float, (u32)(((u32)v) << 16));
}
static __device__ __forceinline__ u16 f2b(float f) {  // RNE f32->bf16
    u32 u = __builtin_bit_cast(u32, f);
    return (u16)((u + 0x7FFFu + ((u >> 16) & 1u)) >> 16);
}
static __device__ __forceinline__ u32 pack2(float a, float b) {
    bf16x2 t; t[0] = (__bf16)a; t[1] = (__bf16)b;
    return __builtin_bit_cast(u32, t);
}

// ---------------------------------------------------------------------------
// LayerNorm: rows 0..4095 = x, 4096..8191 = context. 1024 f32 per row.
// ---------------------------------------------------------------------------
__global__ __launch_bounds__(256)
void ln_kernel(const float* __restrict__ x, const float* __restrict__ ctx,
               const float* __restrict__ gamma, const float* __restrict__ cgamma,
               u16* __restrict__ xn, u16* __restrict__ ctxn)
{
    const int row = blockIdx.x;
    const int tid = threadIdx.x;
    const float* src; const float* g; u16* dst;
    if (row < 4096) { src = x   + (long)row * 1024;          g = gamma;  dst = xn   + (long)row * 1024; }
    else            { src = ctx + (long)(row - 4096) * 1024; g = cgamma; dst = ctxn + (long)(row - 4096) * 1024; }
    float4 v = ((const float4*)src)[tid];
    float s = v.x + v.y + v.z + v.w;
    float q = v.x*v.x + v.y*v.y + v.z*v.z + v.w*v.w;
#pragma unroll
    for (int off = 32; off; off >>= 1) { s += __shfl_xor(s, off); q += __shfl_xor(q, off); }
    __shared__ float r1[4], r2[4];
    if ((tid & 63) == 0) { r1[tid >> 6] = s; r2[tid >> 6] = q; }
    __syncthreads();
    s = r1[0] + r1[1] + r1[2] + r1[3];
    q = r2[0] + r2[1] + r2[2] + r2[3];
    float mu   = s * (1.0f / 1024.0f);
    float var  = q * (1.0f / 1024.0f) - mu * mu;
    float rstd = rsqrtf(var + 1e-5f);
    float4 gv = ((const float4*)g)[tid];
    ushort4 o;
    o.x = f2b((v.x - mu) * rstd * gv.x);
    o.y = f2b((v.y - mu) * rstd * gv.y);
    o.z = f2b((v.z - mu) * rstd * gv.z);
    o.w = f2b((v.w - mu) * rstd * gv.w);
    ((ushort4*)dst)[tid] = o;
}

// ---------------------------------------------------------------------------
// Weight convert: W f32 [K][N] row-major -> Wt bf16 [N][K] row-major, *scale
// ---------------------------------------------------------------------------
__global__ __launch_bounds__(256)
void wconv(const float* __restrict__ W, u16* __restrict__ Wt, int N, int K, float scale)
{
    __shared__ float tile[32][33];
    const int tid = threadIdx.x;
    const int n0 = blockIdx.x * 32;
    const int k0 = blockIdx.y * 32;
    const int r  = tid >> 3;
    const int c4 = (tid & 7) * 4;
    float4 v = *(const float4*)&W[(long)(k0 + r) * N + n0 + c4];
    tile[r][c4 + 0] = v.x; tile[r][c4 + 1] = v.y; tile[r][c4 + 2] = v.z; tile[r][c4 + 3] = v.w;
    __syncthreads();
    ushort4 o;
    o.x = f2b(tile[c4 + 0][r] * scale);
    o.y = f2b(tile[c4 + 1][r] * scale);
    o.z = f2b(tile[c4 + 2][r] * scale);
    o.w = f2b(tile[c4 + 3][r] * scale);
    *(ushort4*)&Wt[(long)(n0 + r) * K + k0 + c4] = o;
}

// ---------------------------------------------------------------------------
// Wff1 convert with a/gate interleave: phys row p <- logical col
// L(p) = (p&16 ? 4096:0) + (p>>5)*16 + (p&15).
// ---------------------------------------------------------------------------
__global__ __launch_bounds__(256)
void wconv_ff1(const float* __restrict__ W, u16* __restrict__ Wt)
{
    __shared__ float tile[32][33];
    const int tid = threadIdx.x;
    const int a  = blockIdx.x;            // 0..255
    const int k0 = blockIdx.y * 32;
    const int r  = tid >> 3;
    const int c4 = (tid & 7) * 4;
    const int srccol = (c4 < 16) ? (a * 16 + c4) : (4096 + a * 16 + (c4 - 16));
    float4 v = *(const float4*)&W[(long)(k0 + r) * 8192 + srccol];
    tile[r][c4 + 0] = v.x; tile[r][c4 + 1] = v.y; tile[r][c4 + 2] = v.z; tile[r][c4 + 3] = v.w;
    __syncthreads();
    ushort4 o;
    o.x = f2b(tile[c4 + 0][r]);
    o.y = f2b(tile[c4 + 1][r]);
    o.z = f2b(tile[c4 + 2][r]);
    o.w = f2b(tile[c4 + 3][r]);
    *(ushort4*)&Wt[(long)(a * 32 + r) * 1024 + k0 + c4] = o;
}

// ---------------------------------------------------------------------------
// kext: [2][2048][64] bf16 K rows; mbias [2][2048] f32 = 0 or -1e30.
// ---------------------------------------------------------------------------
__global__ __launch_bounds__(256)
void kext_build(const float* __restrict__ kvf, const int* __restrict__ mask,
                u16* __restrict__ kext, float* __restrict__ mbias)
{
    const int gid = blockIdx.x * 256 + threadIdx.x;   // 2*2048*8 = 32768
    const int b = gid >> 14;
    const int rem = gid & 16383;
    const int j = rem >> 3;
    const int c = rem & 7;
    const float* src = &kvf[((long)b * 2048 + j) * 128 + c * 8];
    u16 ov[8];
#pragma unroll
    for (int e = 0; e < 8; ++e) ov[e] = f2b(src[e]);
    uint4 w;
    w.x = (u32)ov[0] | ((u32)ov[1] << 16);
    w.y = (u32)ov[2] | ((u32)ov[3] << 16);
    w.z = (u32)ov[4] | ((u32)ov[5] << 16);
    w.w = (u32)ov[6] | ((u32)ov[7] << 16);
    *(uint4*)&kext[((long)b * 2048 + j) * 64 + c * 8] = w;
    if (c == 0) mbias[b * 2048 + j] = mask[b * 2048 + j] ? 0.0f : -1e30f;
}

// ---------------------------------------------------------------------------
// vT [2][64][2048] bf16 <- V columns of kvf f32 [2][2048][128]
// ---------------------------------------------------------------------------
__global__ __launch_bounds__(256)
void vtrans(const float* __restrict__ kvf, u16* __restrict__ vT)
{
    const int j = blockIdx.x * 256 + threadIdx.x;
    const int d = blockIdx.y;
    const int b = blockIdx.z;
    vT[(long)b * 64 * 2048 + (long)d * 2048 + j] =
        f2b(kvf[((long)b * 2048 + j) * 128 + 64 + d]);
}

// ---------------------------------------------------------------------------
// GEMM 128x128 (m97 structure): C = A[M][K] @ Bt[N][K]^T. BK=32, 4 waves.
// EPI: 0 bf16-store, 1 f32-store, 2 f32-accumulate, 4 f32 atomic (split-K).
// Linear block mapping (default round-robin dispatch gives the best per-XCD
// 2D locality: measured FETCH 54MB vs 237MB with a linear-strip XCD remap).
// ---------------------------------------------------------------------------
#define BM 128
#define BN 128
#define BK 32

template<int EPI>
__global__ __launch_bounds__(256, 2)
void gemm_bt(const u16* __restrict__ A, const u16* __restrict__ Bt,
             void* __restrict__ Cv,
             int K, int lda, int ldb, int ldc,
             long aH, long bH, long cH)
{
    __shared__ __align__(16) u16 sm[2][2][BM * BK];
    const int tid  = threadIdx.x;
    const int wave = tid >> 6;
    const int lane = tid & 63;
    const int tn = blockIdx.x * BN;
    const int tm = blockIdx.y * BM;
    const int z  = blockIdx.z;
    A  += (long)z * aH;
    Bt += (long)z * bH;

    const int arow0 = (tid >> 2);
    const int arow1 = 64 + (tid >> 2);
    const int acs0  = (tid & 3) ^ ((arow0 >> 1) & 3);
    const int acs1  = (tid & 3) ^ ((arow1 >> 1) & 3);
    const int nt = K / BK;

#define STAGE(buf, k0)                                                                              \
    do {                                                                                            \
        __builtin_amdgcn_global_load_lds(                                                           \
            (const __attribute__((address_space(1))) void*)(A + (long)(tm + arow0) * lda + (k0) + acs0 * 8),   \
            (__attribute__((address_space(3))) void*)(&sm[buf][0][(wave * 64) * 8]), 16, 0, 0);     \
        __builtin_amdgcn_global_load_lds(                                                           \
            (const __attribute__((address_space(1))) void*)(A + (long)(tm + arow1) * lda + (k0) + acs1 * 8),   \
            (__attribute__((address_space(3))) void*)(&sm[buf][0][(256 + wave * 64) * 8]), 16, 0, 0); \
        __builtin_amdgcn_global_load_lds(                                                           \
            (const __attribute__((address_space(1))) void*)(Bt + (long)(tn + arow0) * ldb + (k0) + acs0 * 8),  \
            (__attribute__((address_space(3))) void*)(&sm[buf][1][(wave * 64) * 8]), 16, 0, 0);     \
        __builtin_amdgcn_global_load_lds(                                                           \
            (const __attribute__((address_space(1))) void*)(Bt + (long)(tn + arow1) * ldb + (k0) + acs1 * 8),  \
            (__attribute__((address_space(3))) void*)(&sm[buf][1][(256 + wave * 64) * 8]), 16, 0, 0); \
    } while (0)

    STAGE(0, 0);

    f32x4 acc[4][4] = {};
    const int wr   = (wave >> 1) * 64;
    const int wc   = (wave & 1) * 64;
    const int frow = lane & 15;
    const int fk   = lane >> 4;

    for (int t = 0; t < nt; ++t) {
        __syncthreads();
        if (t + 1 < nt) STAGE((t + 1) & 1, (t + 1) * BK);
        const int cur = t & 1;
        bf16x8 af[4], bf[4];
#pragma unroll
        for (int m = 0; m < 4; ++m) {
            int row = wr + m * 16 + frow;
            af[m] = *(const bf16x8*)&sm[cur][0][row * BK + ((fk ^ ((row >> 1) & 3)) * 8)];
        }
#pragma unroll
        for (int n = 0; n < 4; ++n) {
            int row = wc + n * 16 + frow;
            bf[n] = *(const bf16x8*)&sm[cur][1][row * BK + ((fk ^ ((row >> 1) & 3)) * 8)];
        }
#pragma unroll
        for (int m = 0; m < 4; ++m)
#pragma unroll
            for (int n = 0; n < 4; ++n)
                acc[m][n] = __builtin_amdgcn_mfma_f32_16x16x32_bf16(af[m], bf[n], acc[m][n], 0, 0, 0);
    }
#undef STAGE

    const long coff = (long)z * cH;
#pragma unroll
    for (int m = 0; m < 4; ++m) {
        const int row0 = tm + wr + m * 16 + fk * 4;
#pragma unroll
        for (int n = 0; n < 4; ++n) {
            const int col = tn + wc + n * 16 + frow;
#pragma unroll
            for (int r = 0; r < 4; ++r) {
                const long off = coff + (long)(row0 + r) * ldc + col;
                const float v = acc[m][n][r];
                if constexpr (EPI == 0)      ((u16*)Cv)[off] = f2b(v);
                else if constexpr (EPI == 1) ((float*)Cv)[off] = v;
                else if constexpr (EPI == 2) ((float*)Cv)[off] += v;
                else                         atomicAdd(&((float*)Cv)[off], v);
            }
        }
    }
}

// ---------------------------------------------------------------------------
// GEMM 256x256, BK=64, 512 thr (8 waves: 2M x 4N), counted-vmcnt pipeline
// (T3+T4): raw s_barrier (no full drain), stage tile t+2 while computing t,
// s_waitcnt vmcnt(8) keeps next tile's 8 loads in flight across barriers.
// LDS 128KB double-buffer; XOR chunk swizzle with pre-swizzled global source.
// Epilogue: fused swiglu over column-interleaved Wff1Tp (pairs nf even=a,
// nf odd=gate). C = gbuf bf16 [4096][4096].
// ---------------------------------------------------------------------------
__global__ __launch_bounds__(512, 2)
void gemm256_ff1(const u16* __restrict__ A, const u16* __restrict__ Bt,
                 u16* __restrict__ C, int K, int lda, int ldb, int ldc)
{
    __shared__ __align__(16) u16 As[2][256 * 64];
    __shared__ __align__(16) u16 Bs[2][256 * 64];
    const int tid  = threadIdx.x;
    const int wave = tid >> 6, lane = tid & 63;
    const int wm = wave >> 2, wn = wave & 3;
    const int frow = lane & 15, fk = lane >> 4;
    const int tn = blockIdx.x * 256;
    const int tm = blockIdx.y * 256;
    const int nt = K >> 6;          // K-tiles of 64 (nt >= 2 required)

    // staging geometry: load i covers slot s = i*512+tid; row = s>>3,
    // phys chunk = s&7 (16B units), src chunk = phys ^ (row&7).
    int arow[4], acs[4];
#pragma unroll
    for (int i = 0; i < 4; ++i) {
        const int slot = i * 512 + tid;
        arow[i] = slot >> 3;
        acs[i]  = ((slot & 7) ^ (arow[i] & 7)) * 8;
    }

#define STAGE256(buf, k0)                                                                            \
    do {                                                                                             \
        _Pragma("unroll")                                                                            \
        for (int i = 0; i < 4; ++i) {                                                                \
            __builtin_amdgcn_global_load_lds(                                                        \
                (const __attribute__((address_space(1))) void*)(A + (long)(tm + arow[i]) * lda + (k0) + acs[i]),  \
                (__attribute__((address_space(3))) void*)(&As[buf][(i * 512 + wave * 64) * 8]), 16, 0, 0);        \
            __builtin_amdgcn_global_load_lds(                                                        \
                (const __attribute__((address_space(1))) void*)(Bt + (long)(tn + arow[i]) * ldb + (k0) + acs[i]), \
                (__attribute__((address_space(3))) void*)(&Bs[buf][(i * 512 + wave * 64) * 8]), 16, 0, 0);        \
        }                                                                                            \
    } while (0)

    // prologue: tiles 0 and 1 in flight; wait oldest 8 (tile 0) landed
    STAGE256(0, 0);
    STAGE256(1, 64);
    asm volatile("s_waitcnt vmcnt(8)" ::: "memory");
    __builtin_amdgcn_sched_barrier(0);
    __builtin_amdgcn_s_barrier();

    f32x4 acc[8][4] = {};

    for (int t = 0; ; ++t) {
        const int cur = t & 1;
        const u16* as = &As[cur][0];
        const u16* bs = &Bs[cur][0];
#pragma unroll
        for (int kk = 0; kk < 2; ++kk) {
            bf16x8 af[8], bfr[4];
#pragma unroll
            for (int mf = 0; mf < 8; ++mf) {
                const int row = wm * 128 + mf * 16 + frow;
                af[mf] = *(const bf16x8*)&as[row * 64 + (((kk * 4 + fk) ^ (row & 7)) * 8)];
            }
#pragma unroll
            for (int nf = 0; nf < 4; ++nf) {
                const int row = wn * 64 + nf * 16 + frow;
                bfr[nf] = *(const bf16x8*)&bs[row * 64 + (((kk * 4 + fk) ^ (row & 7)) * 8)];
            }
            __builtin_amdgcn_s_setprio(1);
#pragma unroll
            for (int mf = 0; mf < 8; ++mf)
#pragma unroll
                for (int nf = 0; nf < 4; ++nf)
                    acc[mf][nf] = __builtin_amdgcn_mfma_f32_16x16x32_bf16(af[mf], bfr[nf], acc[mf][nf], 0, 0, 0);
            __builtin_amdgcn_s_setprio(0);
        }
        if (t == nt - 1) break;
        __builtin_amdgcn_sched_barrier(0);
        __builtin_amdgcn_s_barrier();              // all waves done reading buf cur
        if (t + 2 < nt) {
            STAGE256(cur, (t + 2) << 6);           // refill cur with tile t+2
            asm volatile("s_waitcnt vmcnt(8)" ::: "memory");   // tile t+1 landed
        } else {
            asm volatile("s_waitcnt vmcnt(0)" ::: "memory");   // drain last tile
        }
        __builtin_amdgcn_sched_barrier(0);
        __builtin_amdgcn_s_barrier();              // tile t+1 visible to all
    }
#undef STAGE256

    // epilogue: swiglu. B-rows (wn*64+nf*16): nf even = a, nf odd = gate,
    // silu col = tn/2 + (wn*2 + nf/2)*16 + frow.
#pragma unroll
    for (int mf = 0; mf < 8; ++mf) {
        const int gr = tm + wm * 128 + mf * 16 + fk * 4;
#pragma unroll
        for (int np = 0; np < 4; np += 2) {
            const int scol = (tn >> 1) + (wn * 2 + (np >> 1)) * 16 + frow;
            const f32x4 av = acc[mf][np];
            const f32x4 gv = acc[mf][np + 1];
#pragma unroll
            for (int r = 0; r < 4; ++r) {
                const float g = gv[r];
                const float o = av[r] * g / (1.0f + __expf(-g));
                C[(long)(gr + r) * ldc + scol] = f2b(o);
            }
        }
    }
}

// ---------------------------------------------------------------------------
// Flash attention. Grid (32 qtiles, 16 heads, 2 batches), 256 thr = 4 waves;
// QBLK=64 (16 q/wave), JBLK=64. K/V staged via global_load_lds into double-
// buffered LDS shared by all waves. Mask = f32 bias. 40KB LDS -> 4 blocks/CU.
// ---------------------------------------------------------------------------
__global__ __launch_bounds__(256, 4)
void flash_attn(const u16* __restrict__ qb, const u16* __restrict__ kext,
                const u16* __restrict__ vT, const float* __restrict__ mbias,
                u16* __restrict__ aout)
{
    __shared__ __align__(16) u16 Ksm[2][4096];   // [64 j][64 d], chunk-swizzled
    __shared__ __align__(16) u16 Vsm[2][4096];   // [64 d][64 j], chunk-swizzled
    __shared__ __align__(16) u16 Psm[4][1024];   // per-wave [16 q][64 j], swz
    const int tid  = threadIdx.x;
    const int wave = tid >> 6, lane = tid & 63;
    const int frow = lane & 15, fk = lane >> 4;
    const int b = blockIdx.z, h = blockIdx.y;
    const int q0 = blockIdx.x * 64;

    const u16* kx = kext + (long)b * 2048 * 64;
    const u16* vb = vT   + (long)b * 64 * 2048;
    const float* mbb = mbias + b * 2048;

    const u16* qbase = qb + ((long)(b * 2048 + q0 + wave * 16 + frow)) * 1024 + h * 64;
    bf16x8 bq[2];
#pragma unroll
    for (int kk = 0; kk < 2; ++kk)
        bq[kk] = *(const bf16x8*)&qbase[kk * 32 + fk * 8];

#define FSTAGE(buf, j0s)                                                                             \
    do {                                                                                             \
        _Pragma("unroll")                                                                            \
        for (int i = 0; i < 2; ++i) {                                                                \
            const int slot = i * 256 + tid;                                                          \
            const int row  = slot >> 3;                                                              \
            const int csrc = (slot & 7) ^ (row & 7);                                                 \
            __builtin_amdgcn_global_load_lds(                                                        \
                (const __attribute__((address_space(1))) void*)(kx + (long)((j0s) + row) * 64 + csrc * 8), \
                (__attribute__((address_space(3))) void*)(&Ksm[buf][(i * 256 + wave * 64) * 8]), 16, 0, 0); \
            __builtin_amdgcn_global_load_lds(                                                        \
                (const __attribute__((address_space(1))) void*)(vb + (long)row * 2048 + (j0s) + csrc * 8),  \
                (__attribute__((address_space(3))) void*)(&Vsm[buf][(i * 256 + wave * 64) * 8]), 16, 0, 0); \
        }                                                                                            \
    } while (0)

    FSTAGE(0, 0);

    f32x4 oacc[4] = {};
    float mrun = -1e30f, lrun = 0.0f;
    u16* pw = &Psm[wave][0];

    for (int it = 0; it < 32; ++it) {
        const int j0 = it * 64;
        __syncthreads();
        float4 mb[4];
#pragma unroll
        for (int m = 0; m < 4; ++m)
            mb[m] = *(const float4*)&mbb[j0 + m * 16 + fk * 4];
        if (it + 1 < 32) FSTAGE((it + 1) & 1, (it + 1) * 64);
        const int cur = it & 1;

        f32x4 st[4] = {};
        __builtin_amdgcn_s_setprio(1);
#pragma unroll
        for (int kk = 0; kk < 2; ++kk) {
            bf16x8 ka[4];
#pragma unroll
            for (int m = 0; m < 4; ++m) {
                const int row = m * 16 + frow;
                ka[m] = *(const bf16x8*)&Ksm[cur][row * 64 + (((kk * 4 + fk) ^ (row & 7)) * 8)];
            }
#pragma unroll
            for (int m = 0; m < 4; ++m)
                st[m] = __builtin_amdgcn_mfma_f32_16x16x32_bf16(ka[m], bq[kk], st[m], 0, 0, 0);
        }
        __builtin_amdgcn_s_setprio(0);

        float sb[4][4];
#pragma unroll
        for (int m = 0; m < 4; ++m)
#pragma unroll
            for (int r = 0; r < 4; ++r) sb[m][r] = st[m][r] + (&mb[m].x)[r];
        float pm = fmaxf(
            fmaxf(fmaxf(sb[0][0], sb[0][1]), fmaxf(sb[0][2], sb[0][3])),
            fmaxf(fmaxf(sb[1][0], sb[1][1]), fmaxf(sb[1][2], sb[1][3])));
        pm = fmaxf(pm, fmaxf(
            fmaxf(fmaxf(sb[2][0], sb[2][1]), fmaxf(sb[2][2], sb[2][3])),
            fmaxf(fmaxf(sb[3][0], sb[3][1]), fmaxf(sb[3][2], sb[3][3]))));
        pm = fmaxf(pm, __shfl_xor(pm, 16));
        pm = fmaxf(pm, __shfl_xor(pm, 32));
        const float nm = fmaxf(mrun, pm);
        const float alpha = __expf(mrun - nm);
        mrun = nm;

        float rs = 0.0f;
#pragma unroll
        for (int m = 0; m < 4; ++m) {
            const float p0 = __expf(sb[m][0] - nm);
            const float p1 = __expf(sb[m][1] - nm);
            const float p2 = __expf(sb[m][2] - nm);
            const float p3 = __expf(sb[m][3] - nm);
            rs += (p0 + p1) + (p2 + p3);
            const int chunk = (m * 2 + (fk >> 1)) ^ (frow & 7);
            uint2 w; w.x = pack2(p0, p1); w.y = pack2(p2, p3);
            *(uint2*)&pw[frow * 64 + chunk * 8 + (fk & 1) * 4] = w;
        }
        rs += __shfl_xor(rs, 16);
        rs += __shfl_xor(rs, 32);
        lrun = lrun * alpha + rs;
#pragma unroll
        for (int mo = 0; mo < 4; ++mo)
#pragma unroll
            for (int r = 0; r < 4; ++r) oacc[mo][r] *= alpha;

        __builtin_amdgcn_s_setprio(1);
#pragma unroll
        for (int kkv = 0; kkv < 2; ++kkv) {
            bf16x8 va[4];
#pragma unroll
            for (int mo = 0; mo < 4; ++mo) {
                const int row = mo * 16 + frow;
                va[mo] = *(const bf16x8*)&Vsm[cur][row * 64 + (((kkv * 4 + fk) ^ (row & 7)) * 8)];
            }
            const bf16x8 pb = *(const bf16x8*)&pw[frow * 64 + (((kkv * 4 + fk) ^ (frow & 7)) * 8)];
#pragma unroll
            for (int mo = 0; mo < 4; ++mo)
                oacc[mo] = __builtin_amdgcn_mfma_f32_16x16x32_bf16(va[mo], pb, oacc[mo], 0, 0, 0);
        }
        __builtin_amdgcn_s_setprio(0);
    }
#undef FSTAGE

    const float inv = 1.0f / lrun;
    const long row = (long)b * 2048 + q0 + wave * 16 + frow;
#pragma unroll
    for (int mo = 0; mo < 4; ++mo) {
        uint2 w;
        w.x = pack2(oacc[mo][0] * inv, oacc[mo][1] * inv);
        w.y = pack2(oacc[mo][2] * inv, oacc[mo][3] * inv);
        *(uint2*)&aout[row * 1024 + h * 64 + mo * 16 + fk * 4] = w;
    }
}

// ---------------------------------------------------------------------------
extern "C" void kernel_launch(void* const* d_in, const int* in_sizes, int n_in,
                              void* d_out, int out_size, void* d_ws, size_t ws_size,
                              hipStream_t stream)
{
    const float* x      = (const float*)d_in[0];
    const float* ctx    = (const float*)d_in[1];
    const int*   mask   = (const int*)d_in[2];
    const float* gamma  = (const float*)d_in[3];
    const float* cgamma = (const float*)d_in[4];
    const float* Wq     = (const float*)d_in[5];
    const float* Wkv    = (const float*)d_in[6];
    const float* Wout   = (const float*)d_in[7];
    const float* Wff1   = (const float*)d_in[8];
    const float* Wff2   = (const float*)d_in[9];
    float* out = (float*)d_out;

    char* w = (char*)d_ws;
    auto carveB = [&](long bytes) { char* p = w; w += ((bytes + 255) / 256) * 256; return p; };
    u16*   xn     = (u16*)  carveB(4096L * 1024 * 2);
    u16*   ctxn   = (u16*)  carveB(4096L * 1024 * 2);
    u16*   WqT    = (u16*)  carveB(1024L * 1024 * 2);
    u16*   WkvT   = (u16*)  carveB(128L * 1024 * 2);
    u16*   WoutT  = (u16*)  carveB(1024L * 1024 * 2);
    u16*   Wff1Tp = (u16*)  carveB(8192L * 1024 * 2);
    u16*   Wff2T  = (u16*)  carveB(1024L * 4096 * 2);
    u16*   q      = (u16*)  carveB(4096L * 1024 * 2);
    float* kvf    = (float*)carveB(2L * 2048 * 128 * 4);
    u16*   kext   = (u16*)  carveB(2L * 2048 * 64 * 2);
    float* mbias  = (float*)carveB(2L * 2048 * 4);
    u16*   vT     = (u16*)  carveB(2L * 64 * 2048 * 2);
    u16*   aout   = (u16*)  carveB(4096L * 1024 * 2);
    u16*   gbuf   = (u16*)  carveB(4096L * 4096 * 2);

    dim3 B(256);

    ln_kernel<<<dim3(8192), B, 0, stream>>>(x, ctx, gamma, cgamma, xn, ctxn);
    wconv<<<dim3(32, 32),  B, 0, stream>>>(Wq,   WqT,   1024, 1024, 0.125f);  // q scale folded
    wconv<<<dim3(4, 32),   B, 0, stream>>>(Wkv,  WkvT,  128,  1024, 1.0f);
    wconv<<<dim3(32, 32),  B, 0, stream>>>(Wout, WoutT, 1024, 1024, 1.0f);
    wconv_ff1<<<dim3(256, 32), B, 0, stream>>>(Wff1, Wff1Tp);
    wconv<<<dim3(32, 128), B, 0, stream>>>(Wff2, Wff2T, 1024, 4096, 1.0f);

    // q = xn @ WqT^T : M=4096 N=1024 K=1024
    gemm_bt<0><<<dim3(8, 32, 1), B, 0, stream>>>(xn, WqT, q, 1024, 1024, 1024, 1024, 0, 0, 0);
    // kvf = ctxn @ WkvT^T (f32, split-K x4 atomic): M=4096 N=128 K=1024
    hipMemsetAsync(kvf, 0, 2L * 2048 * 128 * 4, stream);
    gemm_bt<4><<<dim3(1, 32, 4), B, 0, stream>>>(ctxn, WkvT, kvf, 256, 1024, 1024, 128, 256, 256, 0);
    kext_build<<<dim3(128), B, 0, stream>>>(kvf, mask, kext, mbias);
    vtrans<<<dim3(8, 64, 2), B, 0, stream>>>(kvf, vT);

    // fused attention -> aout [b][q][h*64+d]
    flash_attn<<<dim3(32, 16, 2), B, 0, stream>>>(q, kext, vT, mbias, aout);

    // out = aout @ WoutT^T (f32 write)
    gemm_bt<1><<<dim3(8, 32, 1), B, 0, stream>>>(aout, WoutT, out, 1024, 1024, 1024, 1024, 0, 0, 0);
    // gbuf = swiglu(xn @ Wff1Tp^T) : 256^2 counted-vmcnt GEMM, N=8192
    gemm256_ff1<<<dim3(32, 16), dim3(512), 0, stream>>>(xn, Wff1Tp, gbuf, 1024, 1024, 1024, 4096);
    // out += gbuf @ Wff2T^T : K=4096 (f32 accumulate)
    gemm_bt<2><<<dim3(8, 32, 1), B, 0, stream>>>(gbuf, Wff2T, out, 4096, 4096, 4096, 1024, 0, 0, 0);
}